// Round 17
// baseline (3667.508 us; speedup 1.0000x reference)
//
#include <hip/hip_runtime.h>

// LSTM surrogate: B=256, T=512, D=256, U=512, O=64.
// R17 = R12 protocol (proven best: agent swap-at-L3 publish, spread flags,
// sleep-backoff poll, bulk agent h-load) + R3 geometry (M=32 rows/block,
// grid 256 = 1 block/CU: no co-resident contention; 2x MFMA ILP/wave).
// Under the OLD protocol M=32@1/CU beat M=16@2/CU 1.21x (R3 vs R6); this is
// the untested quadrant under the good protocol. L2-homed flags refuted
// twice (R15 hang, R16 writeback storm) — exchange stays at L3.
// 8 batch-groups x 32 rows, 32 unit-groups -> grid 256.

#define Bb 256
#define Tt 512
#define Dd 256
#define Uu 512
#define Oo 64

typedef short bs8 __attribute__((ext_vector_type(8)));      // 8 bf16 (bits)
typedef float f32x4 __attribute__((ext_vector_type(4)));

__device__ __forceinline__ unsigned short f2bf(float f) {
  unsigned u = __float_as_uint(f);
  u += 0x7fffu + ((u >> 16) & 1u);                          // RNE
  return (unsigned short)(u >> 16);
}
__device__ __forceinline__ float bf2f(unsigned short s) {
  return __uint_as_float(((unsigned)s) << 16);
}
__device__ __forceinline__ float sigm(float v) { return 1.0f / (1.0f + __expf(-v)); }
__device__ __forceinline__ float tanhfast(float v) { return 2.0f / (1.0f + __expf(-2.0f * v)) - 1.0f; }

// z LDS: [32 rows][768 k] bf16, row stride 1536 B. XOR swizzle on 16B granules.
__device__ __forceinline__ int zbyte(int row, int k) {
  return (row * 1536 + k * 2) ^ ((row & 7) << 4);
}

// flags: group g (0..7), slot s (0..31) -> bar[(g*32+s)*32] (own 128B line)
__global__ void rnn_init_bar(unsigned* bar) {
  for (int i = threadIdx.x; i < 8 * 32 * 32; i += 256)
    __hip_atomic_store(&bar[i], 0u, __ATOMIC_RELAXED, __HIP_MEMORY_SCOPE_AGENT);
}

__launch_bounds__(256, 1)
__global__ void rnn_lstm_kernel(const float* __restrict__ x, const float* __restrict__ Wx,
                                const float* __restrict__ Wh, const float* __restrict__ bias,
                                const float* __restrict__ Wd, const float* __restrict__ bd,
                                float* __restrict__ out, unsigned short* hbuf, unsigned* bar) {
  __shared__ __align__(16) char zs[32 * 768 * 2];   // 49152 B
  __shared__ float gates[4][32][17];                // 8704 B
  __shared__ float wdl[512][2];                     // 4096 B
  __shared__ float ypart[32][2][8];                 // 2048 B

  const int tid = threadIdx.x;
  const int lane = tid & 63;
  const int wid = tid >> 6;                         // wave 0..3 == gate id
  const int bid = blockIdx.x;
  const int bg = bid & 7;        // batch group 0..7 (XCD-affine under %8 dispatch)
  const int ug = bid >> 3;       // unit group 0..31
  const int b_base = bg * 32;
  const int u_base = ug * 16;
  const int oc0 = ug * 2;

  unsigned* fl = bar + bg * 32 * 32;  // 32 flags, each on its own 128B line

  // ---- weight slice as B-fragments: wave w = gate w; col=lane&15, k=(lane>>4)*8+e ----
  bs8 breg[24];
  {
    const int gc = wid * 512 + u_base + (lane & 15);
    const int kfr = (lane >> 4) * 8;
#pragma unroll
    for (int ks = 0; ks < 24; ++ks) {
      bs8 bb;
#pragma unroll
      for (int e = 0; e < 8; ++e) {
        int kg = ks * 32 + kfr + e;
        float w = (kg < 256) ? Wx[(size_t)kg * 2048 + gc]
                             : Wh[(size_t)(kg - 256) * 2048 + gc];
        bb[e] = (short)f2bf(w);
      }
      breg[ks] = bb;
    }
  }

  // pointwise (tid<128): prow = tid&31, us4 = tid>>5 (0..3), units us4*4+{0..3}
  const int prow = tid & 31;
  const int sec = tid >> 5;                         // 0..7 (y-decode sections of 64 units)
  const int us4 = sec & 3;
  float bi[4], bff[4], bgg[4], boo[4];
  if (tid < 128) {
#pragma unroll
    for (int j = 0; j < 4; ++j) {
      int ugl = u_base + us4 * 4 + j;
      bi[j]  = bias[0 * 512 + ugl];
      bff[j] = bias[1 * 512 + ugl];
      bgg[j] = bias[2 * 512 + ugl];
      boo[j] = bias[3 * 512 + ugl];
    }
  }
  float cst[4] = {0.f, 0.f, 0.f, 0.f};

  union U16 { unsigned long long q[2]; bs8 v; };

  // ---- prologue: Wd slice to LDS, stage x_0 (32 rows), zero h-region ----
#pragma unroll
  for (int i = 0; i < 4; ++i) {
    int c = tid + i * 256;
    wdl[c >> 1][c & 1] = Wd[(size_t)(c >> 1) * Oo + oc0 + (c & 1)];
  }
  {
    int row = tid >> 3;
    int d0 = (tid & 7) * 32;
    const float* xp = x + ((size_t)(b_base + row) * Tt + 0) * Dd + d0;
#pragma unroll
    for (int q = 0; q < 4; ++q) {
      float4 va = *(const float4*)(xp + q * 8);
      float4 vb = *(const float4*)(xp + q * 8 + 4);
      bs8 pk;
      pk[0] = (short)f2bf(va.x); pk[1] = (short)f2bf(va.y);
      pk[2] = (short)f2bf(va.z); pk[3] = (short)f2bf(va.w);
      pk[4] = (short)f2bf(vb.x); pk[5] = (short)f2bf(vb.y);
      pk[6] = (short)f2bf(vb.z); pk[7] = (short)f2bf(vb.w);
      *(bs8*)(zs + zbyte(row, d0 + q * 8)) = pk;
    }
  }
#pragma unroll
  for (int i = 0; i < 8; ++i) {
    int c = tid + i * 256;            // 2048 granules: 32 rows x 64
    int row = c >> 6;
    int u0 = (c & 63) * 8;
    bs8 zz = {0, 0, 0, 0, 0, 0, 0, 0};
    *(bs8*)(zs + zbyte(row, 256 + u0)) = zz;
  }
  __syncthreads();

  const int arow = lane & 15;
  const int akf = (lane >> 4) * 8;
  const int rb = (lane >> 4) * 4;
  const int u16 = lane & 15;

  for (int t = 0; t < Tt; ++t) {
    // ---- gates MFMA: wave's gate, 2 row-tiles (rows 0-15 / 16-31), K=768 ----
    f32x4 aA0 = {0,0,0,0}, aA1 = {0,0,0,0}, aB0 = {0,0,0,0}, aB1 = {0,0,0,0};
#pragma unroll
    for (int ks = 0; ks < 24; ks += 2) {
      bs8 a00 = *(const bs8*)(zs + zbyte(arow,      ks * 32 + akf));
      bs8 a01 = *(const bs8*)(zs + zbyte(arow,      (ks + 1) * 32 + akf));
      bs8 a10 = *(const bs8*)(zs + zbyte(arow + 16, ks * 32 + akf));
      bs8 a11 = *(const bs8*)(zs + zbyte(arow + 16, (ks + 1) * 32 + akf));
      aA0 = __builtin_amdgcn_mfma_f32_16x16x32_bf16(a00, breg[ks], aA0, 0, 0, 0);
      aA1 = __builtin_amdgcn_mfma_f32_16x16x32_bf16(a01, breg[ks + 1], aA1, 0, 0, 0);
      aB0 = __builtin_amdgcn_mfma_f32_16x16x32_bf16(a10, breg[ks], aB0, 0, 0, 0);
      aB1 = __builtin_amdgcn_mfma_f32_16x16x32_bf16(a11, breg[ks + 1], aB1, 0, 0, 0);
    }
    aA0 += aA1; aB0 += aB1;
    // C/D (HW-verified): col = lane&15, row = (lane>>4)*4 + reg
#pragma unroll
    for (int j = 0; j < 4; ++j) {
      gates[wid][rb + j][u16]      = aA0[j];
      gates[wid][16 + rb + j][u16] = aB0[j];
    }
    __syncthreads();                                        // s1

    // ---- pointwise LSTM cell (tid<128); h published via AGENT swap_x2 (L3) ----
    if (tid < 128) {
      unsigned long long hpack = 0ull;
#pragma unroll
      for (int j = 0; j < 4; ++j) {
        int u = us4 * 4 + j;
        float gi = gates[0][prow][u] + bi[j];
        float gf = gates[1][prow][u] + bff[j];
        float gg = gates[2][prow][u] + bgg[j];
        float go = gates[3][prow][u] + boo[j];
        float iv = sigm(gi), fv = sigm(gf), gv = tanhfast(gg), ov = sigm(go);
        float cn = fv * cst[j] + iv * gv;
        cst[j] = cn;
        float hv = ov * tanhfast(cn);
        hpack |= ((unsigned long long)f2bf(hv)) << (16 * j);
      }
      unsigned long long* hp =
          (unsigned long long*)(hbuf + (size_t)(t & 1) * Bb * Uu +
                                (size_t)(b_base + prow) * Uu + u_base + us4 * 4);
      unsigned long long old = __hip_atomic_exchange(hp, hpack, __ATOMIC_RELAXED,
                                                     __HIP_MEMORY_SCOPE_AGENT);
      asm volatile("" :: "v"(old));   // keep the returning (executes-at-L3) form
    }
    // barrier drains each wave's vmcnt: all h-swaps have EXECUTED AT L3 here.
    __syncthreads();                                        // s2
    if (tid == 0) {
      unsigned oldf = __hip_atomic_exchange(&fl[ug * 32], (unsigned)(t + 1),
                                            __ATOMIC_RELAXED, __HIP_MEMORY_SCOPE_AGENT);
      asm volatile("" :: "v"(oldf));
    }

    // ---- barrier window: stage x_{t+1} (x-region of zs is dead) ----
    if (t + 1 < Tt) {
      int row = tid >> 3;
      int d0 = (tid & 7) * 32;
      const float* xp = x + ((size_t)(b_base + row) * Tt + (t + 1)) * Dd + d0;
#pragma unroll
      for (int q = 0; q < 4; ++q) {
        float4 va = *(const float4*)(xp + q * 8);
        float4 vb = *(const float4*)(xp + q * 8 + 4);
        bs8 pk;
        pk[0] = (short)f2bf(va.x); pk[1] = (short)f2bf(va.y);
        pk[2] = (short)f2bf(va.z); pk[3] = (short)f2bf(va.w);
        pk[4] = (short)f2bf(vb.x); pk[5] = (short)f2bf(vb.y);
        pk[6] = (short)f2bf(vb.z); pk[7] = (short)f2bf(vb.w);
        *(bs8*)(zs + zbyte(row, d0 + q * 8)) = pk;
      }
    }

    // ---- barrier window: y_{t-1} partials from LDS h copy ----
    if (t > 0) {
      float s0 = 0.f, s1 = 0.f;
#pragma unroll
      for (int c8 = 0; c8 < 8; ++c8) {
        int k = 256 + sec * 64 + c8 * 8;
        bs8 hv = *(const bs8*)(zs + zbyte(prow, k));
#pragma unroll
        for (int e = 0; e < 8; ++e) {
          float hf = bf2f((unsigned short)hv[e]);
          int u = sec * 64 + c8 * 8 + e;
          s0 += hf * wdl[u][0];
          s1 += hf * wdl[u][1];
        }
      }
      ypart[prow][0][sec] = s0;
      ypart[prow][1][sec] = s1;
    }
    __syncthreads();                                        // s3
    // y reduce on wave0 (64 lanes); poll on wave1 (spread flags + sleep backoff)
    if (t > 0 && tid < 64) {
      int b = tid >> 1, oc = tid & 1;
      float s = bd[oc0 + oc];
#pragma unroll
      for (int q = 0; q < 8; ++q) s += ypart[b][oc][q];
      out[((size_t)(b_base + b) * Tt + (t - 1)) * Oo + oc0 + oc] = s;
    }
    if (wid == 1) {
      for (;;) {
        unsigned v = __hip_atomic_load(&fl[(lane & 31) * 32], __ATOMIC_RELAXED,
                                       __HIP_MEMORY_SCOPE_AGENT);
        if (!__any((int)(v < (unsigned)(t + 1)))) break;
        __builtin_amdgcn_s_sleep(2);
      }
    }
    __builtin_amdgcn_sched_barrier(0);
    __syncthreads();                                        // s4

    // ---- stage h_t from hbuf[t&1] (bulk agent loads: L3-coherent, proven) ----
    {
      const unsigned short* hsrc = hbuf + (size_t)(t & 1) * Bb * Uu;
#pragma unroll
      for (int i = 0; i < 8; ++i) {
        int c = tid + i * 256;
        int row = c >> 6;
        int u0 = (c & 63) * 8;
        const unsigned long long* p =
            (const unsigned long long*)(hsrc + (size_t)(b_base + row) * Uu + u0);
        U16 uu;
        uu.q[0] = __hip_atomic_load(p, __ATOMIC_RELAXED, __HIP_MEMORY_SCOPE_AGENT);
        uu.q[1] = __hip_atomic_load(p + 1, __ATOMIC_RELAXED, __HIP_MEMORY_SCOPE_AGENT);
        *(bs8*)(zs + zbyte(row, 256 + u0)) = uu.v;
      }
    }
    __syncthreads();                                        // s5
  }

  // ---- epilogue: y_{T-1} from zs.h (= h_{T-1} staged by final iteration) ----
  {
    float s0 = 0.f, s1 = 0.f;
#pragma unroll
    for (int c8 = 0; c8 < 8; ++c8) {
      int k = 256 + sec * 64 + c8 * 8;
      bs8 hv = *(const bs8*)(zs + zbyte(prow, k));
#pragma unroll
      for (int e = 0; e < 8; ++e) {
        float hf = bf2f((unsigned short)hv[e]);
        int u = sec * 64 + c8 * 8 + e;
        s0 += hf * wdl[u][0];
        s1 += hf * wdl[u][1];
      }
    }
    ypart[prow][0][sec] = s0;
    ypart[prow][1][sec] = s1;
  }
  __syncthreads();
  if (tid < 64) {
    int b = tid >> 1, oc = tid & 1;
    float s = bd[oc0 + oc];
#pragma unroll
    for (int q = 0; q < 8; ++q) s += ypart[b][oc][q];
    out[((size_t)(b_base + b) * Tt + (Tt - 1)) * Oo + oc0 + oc] = s;
  }
}

extern "C" void kernel_launch(void* const* d_in, const int* in_sizes, int n_in,
                              void* d_out, int out_size, void* d_ws, size_t ws_size,
                              hipStream_t stream) {
  const float* x  = (const float*)d_in[0];
  const float* Wx = (const float*)d_in[1];
  const float* Wh = (const float*)d_in[2];
  const float* bs = (const float*)d_in[3];
  const float* Wd = (const float*)d_in[4];
  const float* bd = (const float*)d_in[5];
  float* out = (float*)d_out;

  unsigned short* hbuf = (unsigned short*)d_ws;                       // 512 KiB
  unsigned* bar = (unsigned*)((char*)d_ws + (size_t)2 * Bb * Uu * 2); // 8g * 32 flags * 128B

  rnn_init_bar<<<1, 256, 0, stream>>>(bar);
  rnn_lstm_kernel<<<dim3(256), dim3(256), 0, stream>>>(x, Wx, Wh, bs, Wd, bd, out, hbuf, bar);
}